// Round 1
// baseline (725.301 us; speedup 1.0000x reference)
//
#include <hip/hip_runtime.h>
#include <hip/hip_bf16.h>

typedef __bf16 bf16x8 __attribute__((ext_vector_type(8)));
typedef float f32x4 __attribute__((ext_vector_type(4)));

#define NB 16384        // batch
#define NE 8            // experts
#define NHID 256        // expert hidden
#define NT 2            // tasks

__device__ __forceinline__ unsigned short f2bf(float f) {
  unsigned u = __float_as_uint(f);
  u += 0x7fff + ((u >> 16) & 1);   // round-to-nearest-even
  return (unsigned short)(u >> 16);
}
__device__ __forceinline__ float bf2f(unsigned short s) {
  return __uint_as_float(((unsigned)s) << 16);
}

// ---------------- 1. gather + concat + bf16 cast ----------------
// x[b, 0:128] = user_table[uidx[b]], x[b,128:256] = item_table[iidx[b]]
__global__ void gather_kernel(const int* __restrict__ uidx,
                              const int* __restrict__ iidx,
                              const float* __restrict__ ut,
                              const float* __restrict__ it,
                              float* __restrict__ xf,
                              unsigned short* __restrict__ xbf) {
  int s = blockIdx.x * 4 + (threadIdx.x >> 6);
  int lane = threadIdx.x & 63;
  const float* src = (lane < 32)
      ? ut + (size_t)uidx[s] * 128 + lane * 4
      : it + (size_t)iidx[s] * 128 + (lane - 32) * 4;
  float4 v = *(const float4*)src;
  int off = s * 256 + lane * 4;
  *(float4*)(xf + off) = v;
  ushort4 bv;
  bv.x = f2bf(v.x); bv.y = f2bf(v.y); bv.z = f2bf(v.z); bv.w = f2bf(v.w);
  *(ushort4*)(xbf + off) = bv;
}

// ---------------- 2. weight prep: transpose to [N][K] bf16 ----------------
__global__ void prep_kernel(const float* __restrict__ eW1,
                            const float* __restrict__ eW2,
                            const float* __restrict__ tW1,
                            unsigned short* __restrict__ w1t,
                            unsigned short* __restrict__ w2t,
                            unsigned short* __restrict__ tw1t) {
  int blk = blockIdx.x;
  int k = threadIdx.x;
  if (blk < 2048) {           // expert weights: e in [0,8), n in [0,256)
    int e = blk >> 8, n = blk & 255;
    w1t[(e * 256 + n) * 256 + k] = f2bf(eW1[(e * 256 + k) * 256 + n]);
    w2t[(e * 256 + n) * 256 + k] = f2bf(eW2[(e * 256 + k) * 256 + n]);
  } else {                    // tower1 weights: t in [0,2), n in [0,128)
    int idx = blk - 2048;
    int t = idx >> 7, n = idx & 127;
    tw1t[(t * 128 + n) * 256 + k] = f2bf(tW1[(t * 256 + k) * 128 + n]);
  }
}

// ---------------- 3. gates (fp32, softmax over E=8) ----------------
__global__ void gate_kernel(const float* __restrict__ xf,
                            const float* __restrict__ gW,
                            const float* __restrict__ gb,
                            float* __restrict__ gates) {
  int idx = blockIdx.x * 256 + threadIdx.x;  // t*16384 + b
  int t = idx >> 14, b = idx & 16383;
  float acc[8] = {0.f, 0.f, 0.f, 0.f, 0.f, 0.f, 0.f, 0.f};
  const float4* x4 = (const float4*)(xf + b * 256);
  const float* gwt = gW + t * 2048;          // [256][8]
  for (int k4 = 0; k4 < 64; ++k4) {
    float4 xv = x4[k4];
    const float* gp = gwt + k4 * 32;
    float xs4[4] = {xv.x, xv.y, xv.z, xv.w};
#pragma unroll
    for (int j = 0; j < 4; ++j)
#pragma unroll
      for (int e = 0; e < 8; ++e) acc[e] += xs4[j] * gp[j * 8 + e];
  }
  float mx = -1e30f;
#pragma unroll
  for (int e = 0; e < 8; ++e) {
    acc[e] += gb[t * 8 + e];
    mx = fmaxf(mx, acc[e]);
  }
  float s = 0.f;
#pragma unroll
  for (int e = 0; e < 8; ++e) { acc[e] = expf(acc[e] - mx); s += acc[e]; }
  float inv = 1.f / s;
#pragma unroll
  for (int e = 0; e < 8; ++e) gates[idx * 8 + e] = acc[e] * inv;
}

// ---------------- 4. fused expert L1+L2 (bf16 MFMA) ----------------
// grid (B/64, E); block 256 = 4 waves; wave w covers cols [64w,64w+64)
// per wave: 4x4 tiles of 16x16, acc = 64 VGPR
__global__ __launch_bounds__(256, 2) void expert_kernel(
    const unsigned short* __restrict__ xbf, const unsigned short* __restrict__ w1t,
    const unsigned short* __restrict__ w2t, const float* __restrict__ eb1,
    const float* __restrict__ eb2, unsigned short* __restrict__ eo) {
  __shared__ unsigned short Xs[64 * 40];     // [64 rows][32k + 8 pad]
  __shared__ unsigned short Ws[256 * 40];    // [256 n][32k + 8 pad]
  __shared__ unsigned short H1s[64 * 264];   // [64 rows][256 + 8 pad]

  const int b0 = blockIdx.x * 64;
  const int e = blockIdx.y;
  const int tid = threadIdx.x;
  const int lane = tid & 63;
  const int w = tid >> 6;
  const int m = lane & 15;
  const int q = lane >> 4;
  const int k0 = q * 8;

  f32x4 zero4 = {0.f, 0.f, 0.f, 0.f};
  f32x4 acc[4][4];
#pragma unroll
  for (int rt = 0; rt < 4; ++rt)
#pragma unroll
    for (int ct = 0; ct < 4; ++ct) acc[rt][ct] = zero4;

  // ---- phase 1: h1 = relu(x @ W1 + b1) ----
  for (int kt = 0; kt < 8; ++kt) {
    const int kb = kt * 32;
#pragma unroll
    for (int i = 0; i < 2; ++i) {
      int idx = tid + i * 256;
      int r = idx >> 3, c = (idx & 7) * 4;
      *(ushort4*)(Xs + r * 40 + c) =
          *(const ushort4*)(xbf + (b0 + r) * 256 + kb + c);
    }
#pragma unroll
    for (int i = 0; i < 8; ++i) {
      int idx = tid + i * 256;
      int n = idx >> 3, c = (idx & 7) * 4;
      *(ushort4*)(Ws + n * 40 + c) =
          *(const ushort4*)(w1t + (e * 256 + n) * 256 + kb + c);
    }
    __syncthreads();
    bf16x8 a[4], bb[4];
#pragma unroll
    for (int rt = 0; rt < 4; ++rt)
      a[rt] = *(const bf16x8*)(Xs + (rt * 16 + m) * 40 + k0);
#pragma unroll
    for (int ct = 0; ct < 4; ++ct)
      bb[ct] = *(const bf16x8*)(Ws + (w * 64 + ct * 16 + m) * 40 + k0);
#pragma unroll
    for (int rt = 0; rt < 4; ++rt)
#pragma unroll
      for (int ct = 0; ct < 4; ++ct)
        acc[rt][ct] = __builtin_amdgcn_mfma_f32_16x16x32_bf16(
            a[rt], bb[ct], acc[rt][ct], 0, 0, 0);
    __syncthreads();
  }
  // h1 -> LDS (relu + bias, bf16). C-layout: col=lane&15, row=q*4+reg
#pragma unroll
  for (int ct = 0; ct < 4; ++ct) {
    int col = w * 64 + ct * 16 + m;
    float bias = eb1[e * 256 + col];
#pragma unroll
    for (int rt = 0; rt < 4; ++rt)
#pragma unroll
      for (int r = 0; r < 4; ++r) {
        int row = rt * 16 + q * 4 + r;
        H1s[row * 264 + col] = f2bf(fmaxf(acc[rt][ct][r] + bias, 0.f));
      }
  }
#pragma unroll
  for (int rt = 0; rt < 4; ++rt)
#pragma unroll
    for (int ct = 0; ct < 4; ++ct) acc[rt][ct] = zero4;
  __syncthreads();

  // ---- phase 2: expert_out = relu(h1 @ W2 + b2) ----
  for (int kt = 0; kt < 8; ++kt) {
    const int kb = kt * 32;
#pragma unroll
    for (int i = 0; i < 8; ++i) {
      int idx = tid + i * 256;
      int n = idx >> 3, c = (idx & 7) * 4;
      *(ushort4*)(Ws + n * 40 + c) =
          *(const ushort4*)(w2t + (e * 256 + n) * 256 + kb + c);
    }
    __syncthreads();
    bf16x8 a[4], bb[4];
#pragma unroll
    for (int rt = 0; rt < 4; ++rt)
      a[rt] = *(const bf16x8*)(H1s + (rt * 16 + m) * 264 + kb + k0);
#pragma unroll
    for (int ct = 0; ct < 4; ++ct)
      bb[ct] = *(const bf16x8*)(Ws + (w * 64 + ct * 16 + m) * 40 + k0);
#pragma unroll
    for (int rt = 0; rt < 4; ++rt)
#pragma unroll
      for (int ct = 0; ct < 4; ++ct)
        acc[rt][ct] = __builtin_amdgcn_mfma_f32_16x16x32_bf16(
            a[rt], bb[ct], acc[rt][ct], 0, 0, 0);
    __syncthreads();
  }
  // epilogue: eo[b][e][h] bf16
#pragma unroll
  for (int ct = 0; ct < 4; ++ct) {
    int col = w * 64 + ct * 16 + m;
    float bias = eb2[e * 256 + col];
#pragma unroll
    for (int rt = 0; rt < 4; ++rt)
#pragma unroll
      for (int r = 0; r < 4; ++r) {
        int bg = b0 + rt * 16 + q * 4 + r;
        eo[(bg * 8 + e) * 256 + col] = f2bf(fmaxf(acc[rt][ct][r] + bias, 0.f));
      }
  }
}

// ---------------- 5. gated combine -> mmoe (bf16) ----------------
__global__ void combine_kernel(const unsigned short* __restrict__ eo,
                               const float* __restrict__ gates,
                               unsigned short* __restrict__ mmoe) {
  int b = blockIdx.x;
  int h = threadIdx.x;
  float a0 = 0.f, a1 = 0.f;
#pragma unroll
  for (int e = 0; e < 8; ++e) {
    float v = bf2f(eo[(b * 8 + e) * 256 + h]);
    a0 += gates[b * 8 + e] * v;
    a1 += gates[(16384 + b) * 8 + e] * v;
  }
  mmoe[b * 256 + h] = f2bf(a0);
  mmoe[(16384 + b) * 256 + h] = f2bf(a1);
}

// ---------------- 6. towers: MFMA tower1 + shuffle-reduced tower2 ----------------
// grid (B/32, T); block 256 = 4 waves; wave: rows 16*(w&1), cols 64*(w>>1)
__global__ __launch_bounds__(256) void tower_kernel(
    const unsigned short* __restrict__ mmoe, const unsigned short* __restrict__ tw1t,
    const float* __restrict__ tb1, const float* __restrict__ tW2,
    const float* __restrict__ tb2, float* __restrict__ out) {
  __shared__ unsigned short MMs[32 * 264];
  __shared__ unsigned short W1s[128 * 40];
  __shared__ float red[32][2];
  const int b0 = blockIdx.x * 32;
  const int t = blockIdx.y;
  const int tid = threadIdx.x;
  const int lane = tid & 63;
  const int w = tid >> 6;
  const int m = lane & 15;
  const int q = lane >> 4;
  const int k0 = q * 8;
  const int rowbase = 16 * (w & 1);
  const int colbase = 64 * (w >> 1);

#pragma unroll
  for (int i = 0; i < 8; ++i) {
    int idx = tid + i * 256;
    int r = idx >> 6, c = (idx & 63) * 4;
    *(ushort4*)(MMs + r * 264 + c) =
        *(const ushort4*)(mmoe + (t * 16384 + b0 + r) * 256 + c);
  }
  f32x4 zero4 = {0.f, 0.f, 0.f, 0.f};
  f32x4 acc[4];
#pragma unroll
  for (int ct = 0; ct < 4; ++ct) acc[ct] = zero4;

  for (int kt = 0; kt < 8; ++kt) {
#pragma unroll
    for (int i = 0; i < 4; ++i) {
      int idx = tid + i * 256;
      int n = idx >> 3, c = (idx & 7) * 4;
      *(ushort4*)(W1s + n * 40 + c) =
          *(const ushort4*)(tw1t + (t * 128 + n) * 256 + kt * 32 + c);
    }
    __syncthreads();   // also covers initial MMs load on kt==0
    bf16x8 a = *(const bf16x8*)(MMs + (rowbase + m) * 264 + kt * 32 + k0);
#pragma unroll
    for (int ct = 0; ct < 4; ++ct) {
      bf16x8 bfr = *(const bf16x8*)(W1s + (colbase + ct * 16 + m) * 40 + k0);
      acc[ct] = __builtin_amdgcn_mfma_f32_16x16x32_bf16(a, bfr, acc[ct], 0, 0, 0);
    }
    __syncthreads();
  }
  // tower2: th = relu(acc + tb1); partial = th * tW2; reduce over 128 cols
  float pr[4] = {0.f, 0.f, 0.f, 0.f};
#pragma unroll
  for (int ct = 0; ct < 4; ++ct) {
    int n = colbase + ct * 16 + m;
    float bias = tb1[t * 128 + n];
    float w2v = tW2[t * 128 + n];
#pragma unroll
    for (int r = 0; r < 4; ++r)
      pr[r] += fmaxf(acc[ct][r] + bias, 0.f) * w2v;
  }
#pragma unroll
  for (int d = 1; d < 16; d <<= 1)
#pragma unroll
    for (int r = 0; r < 4; ++r) pr[r] += __shfl_xor(pr[r], d);
  if (m == 0) {
#pragma unroll
    for (int r = 0; r < 4; ++r) red[rowbase + q * 4 + r][w >> 1] = pr[r];
  }
  __syncthreads();
  if (tid < 32) out[t * 16384 + b0 + tid] = red[tid][0] + red[tid][1] + tb2[t];
}

extern "C" void kernel_launch(void* const* d_in, const int* in_sizes, int n_in,
                              void* d_out, int out_size, void* d_ws, size_t ws_size,
                              hipStream_t stream) {
  (void)in_sizes; (void)n_in; (void)out_size; (void)ws_size;
  const int*   uidx = (const int*)d_in[0];
  const int*   iidx = (const int*)d_in[1];
  const float* ut   = (const float*)d_in[2];
  const float* it   = (const float*)d_in[3];
  const float* eW1  = (const float*)d_in[4];
  const float* eb1  = (const float*)d_in[5];
  const float* eW2  = (const float*)d_in[6];
  const float* eb2  = (const float*)d_in[7];
  const float* gW   = (const float*)d_in[8];
  const float* gb   = (const float*)d_in[9];
  const float* tW1  = (const float*)d_in[10];
  const float* tb1  = (const float*)d_in[11];
  const float* tW2  = (const float*)d_in[12];
  const float* tb2  = (const float*)d_in[13];
  float* out = (float*)d_out;

  char* p = (char*)d_ws;
  float* xf = (float*)p;             p += (size_t)NB * 256 * 4;      // 16 MB
  unsigned short* xbf = (unsigned short*)p;  p += (size_t)NB * 256 * 2;   // 8 MB
  unsigned short* w1t = (unsigned short*)p;  p += (size_t)NE * 256 * 256 * 2;  // 1 MB
  unsigned short* w2t = (unsigned short*)p;  p += (size_t)NE * 256 * 256 * 2;  // 1 MB
  unsigned short* tw1t = (unsigned short*)p; p += (size_t)NT * 128 * 256 * 2;  // 128 KB
  float* gates = (float*)p;          p += (size_t)NT * NB * 8 * 4;   // 1 MB
  unsigned short* eo = (unsigned short*)p;   p += (size_t)NB * NE * 256 * 2;   // 64 MB
  unsigned short* mmoe = (unsigned short*)p; p += (size_t)NT * NB * 256 * 2;   // 16 MB

  gather_kernel<<<NB / 4, 256, 0, stream>>>(uidx, iidx, ut, it, xf, xbf);
  prep_kernel<<<2048 + 256, 256, 0, stream>>>(eW1, eW2, tW1, w1t, w2t, tw1t);
  gate_kernel<<<(NT * NB) / 256, 256, 0, stream>>>(xf, gW, gb, gates);
  expert_kernel<<<dim3(NB / 64, NE), 256, 0, stream>>>(xbf, w1t, w2t, eb1, eb2, eo);
  combine_kernel<<<NB, 256, 0, stream>>>(eo, gates, mmoe);
  tower_kernel<<<dim3(NB / 32, NT), 256, 0, stream>>>(mmoe, tw1t, tb1, tW2, tb2, out);
}